// Round 8
// baseline (284.988 us; speedup 1.0000x reference)
//
#include <hip/hip_runtime.h>

using short8  = __attribute__((ext_vector_type(8))) short;
using short4v = __attribute__((ext_vector_type(4))) short;
using floatx4 = __attribute__((ext_vector_type(4))) float;

#define MFMA_B16(a, b, c) __builtin_amdgcn_mfma_f32_16x16x32_bf16(a, b, c, 0, 0, 0)

__device__ __forceinline__ short f2bf(float f) {
  union { float f; unsigned u; } v; v.f = f;
  unsigned r = v.u + 0x7fffu + ((v.u >> 16) & 1u);
  return (short)(r >> 16);
}
// truncating cast (P>=0; bias cancels between PV numerator and ones-column denom)
__device__ __forceinline__ short f2bf_rtz(float f) {
  union { float f; unsigned u; } v; v.f = f;
  return (short)(v.u >> 16);
}

// async global->LDS, 16B per lane; lds dest = wave-uniform base + lane*16
__device__ __forceinline__ void gload_lds16(const short* g, short* l) {
  __builtin_amdgcn_global_load_lds(
      (const __attribute__((address_space(1))) unsigned int*)g,
      (__attribute__((address_space(3))) unsigned int*)l, 16, 0, 0);
}

// ---------------- prep: cast x -> bf16  +  transpose/cast weights ----------------
__global__ __launch_bounds__(256) void prep(
    const float4* __restrict__ x, short4v* __restrict__ xb,
    const float* __restrict__ w0, const float* __restrict__ w1,
    const float* __restrict__ w2, const float* __restrict__ w3,
    short* __restrict__ wT) {
  __shared__ float tile[32][33];
  int blk = blockIdx.x;
  if (blk < 8192) {
    int i = blk * 256 + threadIdx.x;
    float4 v = x[i];
    short4v o = { f2bf(v.x), f2bf(v.y), f2bf(v.z), f2bf(v.w) };
    xb[i] = o;
  } else {
    int r = blk - 8192;
    int z = r >> 10; r &= 1023;
    const float* w = z == 0 ? w0 : (z == 1 ? w1 : (z == 2 ? w2 : w3));
    short* out = wT + (size_t)z * 1024 * 1024;
    int n0 = (r & 31) * 32, k0 = (r >> 5) * 32;
    int tx = threadIdx.x & 31, ty = threadIdx.x >> 5;
#pragma unroll
    for (int i = 0; i < 4; ++i)
      tile[ty + i * 8][tx] = w[(size_t)(k0 + ty + i * 8) * 1024 + n0 + tx];
    __syncthreads();
#pragma unroll
    for (int i = 0; i < 4; ++i)
      out[(size_t)(n0 + ty + i * 8) * 1024 + k0 + tx] = f2bf(tile[tx][ty + i * 8]);
  }
}

// ---------------- QKV GEMM: BM=256 BN=256 BK=64, fragment-pipelined ----------------
// ROUND-8 CHANGE (single variable vs round 5): intra-tile fragment pipelining.
// Each phase issues the ds_reads for a LATER phase into a disjoint register
// set, so the LDS service of those reads hides under this phase's MFMA
// window instead of serializing ahead of it (rounds 2-7 all paid
// ~750 cyc LDS service + 512 cyc MFMA per phase, serial).
//   p0: read aF0(A-mh0), bF0(B-nh0), bF1(B-nh1); mm(aF0,bF0)   [waits 12 reads]
//   p1: read aF1(A-mh1); stage A0,A2(t+2);       mm(aF0,bF1)   [bF1 already serviced]
//   p2: stage B0..B3(t+2);                        mm(aF1,bF0)   [aF1 serviced under p1]
//   p3: stage A1,A3(t+2);                         mm(aF1,bF1);  vmcnt(8)
// Stage-slot safety (unchanged discipline): A q0,q2 reads retire at p0's MFMA
// (lgkm) + p0-end barrier -> p1 stage safe; B reads retire by p1-end -> p2
// safe; A q1,q3 retire by p2-end -> p3 safe. vmcnt(8) at p3 = tile t+2's 8
// units outstanding => t+1 fully landed; barrier makes it block-wide.
// Registers: aF0/1 64 + bF0/1 32 + acc 128 (AGPR) + addr ~25 ~= 250 <= 256.
__global__ __launch_bounds__(512, 2) void gemm_qkv(
    const short* __restrict__ xb, const short* __restrict__ wT,
    const float* __restrict__ bq, const float* __restrict__ bk,
    const float* __restrict__ bv, short* __restrict__ qkv) {
  __shared__ __align__(16) short As[2 * 16384];
  __shared__ __align__(16) short Bs[2 * 16384];
  int bid = blockIdx.x;          // 0..383 (1.5 rounds)
  int xcd = bid & 7;
  int idx = bid >> 3;            // 0..47
  int z   = idx >> 4;            // 0..2
  int r   = idx & 15;            // 0..15
  int mb  = xcd * 4 + (r & 3);   // 4-m stripe per XCD
  int nb  = r >> 2;              // 0..3
  const short* wt = wT + (size_t)z * 1024 * 1024;
  const float* bias = z == 0 ? bq : (z == 1 ? bk : bv);
  short* out = qkv + (size_t)z * 8192 * 1024;
  int m0 = mb * 256, n0 = nb * 256;

  const int tid = threadIdx.x;
  const int w = tid >> 6, lane = tid & 63, quad = lane >> 4, l16 = lane & 15;
  const int wm = w >> 2, wn = w & 3;
  const int srow = tid >> 3;                       // 0..63
  const int scol = ((tid & 7) ^ (srow & 7)) * 8;   // inverse-swizzled source col

  floatx4 zf = {0.f, 0.f, 0.f, 0.f};
  floatx4 acc[8][4];
#pragma unroll
  for (int i = 0; i < 8; ++i)
#pragma unroll
    for (int j = 0; j < 4; ++j) acc[i][j] = zf;

  const short* gA = xb + (size_t)(m0 + srow) * 1024 + scol;
  const short* gB = wt + (size_t)(n0 + srow) * 1024 + scol;

  auto stA = [&](int buf, int q, int kt) {
    gload_lds16(gA + (size_t)q * 64 * 1024 + kt * 64,
                As + buf * 16384 + q * 4096 + w * 512);
  };
  auto stB = [&](int buf, int q, int kt) {
    gload_lds16(gB + (size_t)q * 64 * 1024 + kt * 64,
                Bs + buf * 16384 + q * 4096 + w * 512);
  };

  short8 aF0[8], aF1[8], bF0[4], bF1[4];
  auto ldA = [&](int buf, int mh, short8* dst) {
    const char* base = (const char*)(As + buf * 16384);
#pragma unroll
    for (int m = 0; m < 4; ++m)
#pragma unroll
      for (int kk = 0; kk < 2; ++kk) {
        int row = wm * 128 + mh * 64 + m * 16 + l16;
        int off = row * 128 + kk * 64 + quad * 16;
        off ^= (row & 7) << 4;
        dst[m * 2 + kk] = *(const short8*)(base + off);
      }
  };
  auto ldB = [&](int buf, int nh, short8* dst) {
    const char* base = (const char*)(Bs + buf * 16384);
#pragma unroll
    for (int n = 0; n < 2; ++n)
#pragma unroll
      for (int kk = 0; kk < 2; ++kk) {
        int row = wn * 64 + nh * 32 + n * 16 + l16;
        int off = row * 128 + kk * 64 + quad * 16;
        off ^= (row & 7) << 4;
        dst[n * 2 + kk] = *(const short8*)(base + off);
      }
  };
  auto mm = [&](const short8* a, const short8* b, int mh, int nh) {
#pragma unroll
    for (int m = 0; m < 4; ++m)
#pragma unroll
      for (int n = 0; n < 2; ++n)
#pragma unroll
        for (int kk = 0; kk < 2; ++kk)
          acc[mh * 4 + m][nh * 2 + n] =
              MFMA_B16(a[m * 2 + kk], b[n * 2 + kk], acc[mh * 4 + m][nh * 2 + n]);
  };

  // prologue: tile0 (8 units) + tile1 (8 units); wait tile0 landed
  stA(0, 0, 0); stA(0, 1, 0); stA(0, 2, 0); stA(0, 3, 0);
  stB(0, 0, 0); stB(0, 1, 0); stB(0, 2, 0); stB(0, 3, 0);
  stA(1, 0, 1); stA(1, 1, 1); stA(1, 2, 1); stA(1, 3, 1);
  stB(1, 0, 1); stB(1, 1, 1); stB(1, 2, 1); stB(1, 3, 1);
  asm volatile("s_waitcnt vmcnt(8)" ::: "memory");
  __builtin_amdgcn_s_barrier();

#pragma unroll 2
  for (int t = 0; t < 16; ++t) {
    const int cb = t & 1;
    // ---- p0: read aF0 + both B-frag sets; MFMA waits only aF0+bF0
    ldA(cb, 0, aF0);
    ldB(cb, 0, bF0);
    ldB(cb, 1, bF1);
    __builtin_amdgcn_s_setprio(1); mm(aF0, bF0, 0, 0); __builtin_amdgcn_s_setprio(0);
    __builtin_amdgcn_s_barrier();
    // ---- p1: read aF1 (service hides under this MFMA); stage A0,A2(t+2)
    ldA(cb, 1, aF1);
    if (t + 2 < 16) { stA(cb, 0, t + 2); stA(cb, 2, t + 2); }
    __builtin_amdgcn_s_setprio(1); mm(aF0, bF1, 0, 1); __builtin_amdgcn_s_setprio(0);
    __builtin_amdgcn_s_barrier();
    // ---- p2: stage B0..B3(t+2); MFMA on already-resident aF1,bF0
    if (t + 2 < 16) {
      stB(cb, 0, t + 2); stB(cb, 1, t + 2);
      stB(cb, 2, t + 2); stB(cb, 3, t + 2);
    }
    __builtin_amdgcn_s_setprio(1); mm(aF1, bF0, 1, 0); __builtin_amdgcn_s_setprio(0);
    __builtin_amdgcn_s_barrier();
    // ---- p3: stage A1,A3(t+2); MFMA; counted vmcnt boundary
    if (t + 2 < 16) {
      stA(cb, 1, t + 2); stA(cb, 3, t + 2);
      __builtin_amdgcn_s_setprio(1); mm(aF1, bF1, 1, 1); __builtin_amdgcn_s_setprio(0);
      asm volatile("s_waitcnt vmcnt(8)" ::: "memory");  // tile t+1 landed
    } else {
      __builtin_amdgcn_s_setprio(1); mm(aF1, bF1, 1, 1); __builtin_amdgcn_s_setprio(0);
      asm volatile("s_waitcnt vmcnt(0)" ::: "memory");  // tail drain
    }
    __builtin_amdgcn_s_barrier();
  }

  // epilogue: (B,H,L,D) bf16; Q pre-scaled by log2(e)/8 for exp2 attention
  float qs = (z == 0) ? 0.125f * 1.44269504f : 1.0f;
#pragma unroll
  for (int mf = 0; mf < 8; ++mf)
#pragma unroll
    for (int nf = 0; nf < 4; ++nf)
#pragma unroll
      for (int rg = 0; rg < 4; ++rg) {
        int m = m0 + wm * 128 + mf * 16 + quad * 4 + rg;
        int cc = n0 + wn * 64 + nf * 16 + l16;
        float v = (acc[mf][nf][rg] + bias[cc]) * qs;
        int b = m >> 12, l = m & 4095;
        int hh = cc >> 6, d = cc & 63;
        out[((size_t)(b * 16 + hh) * 4096 + l) * 64 + d] = f2bf(v);
      }
}

// ---------------- windowed attention (unchanged) ----------------
__global__ __launch_bounds__(256) void attn_kern(const short* __restrict__ qkv,
                                                 short* __restrict__ attnb) {
  const int L = 4096, H = 16;
  int n = blockIdx.x, h = blockIdx.y, b = blockIdx.z;
  const size_t hs = (size_t)L * 64;
  const short* Qp = qkv + (size_t)(b * H + h) * hs;
  const short* Kp = qkv + (size_t)8192 * 1024 + (size_t)(b * H + h) * hs;
  const short* Vp = qkv + (size_t)2 * 8192 * 1024 + (size_t)(b * H + h) * hs;

  __shared__ __align__(16) short kt[128][72];
  __shared__ __align__(16) short vt[64][136];   // vt[d][key]
  __shared__ __align__(16) short pl[4][32][136];

  int tid = threadIdx.x, w = tid >> 6, lane = tid & 63, quad = lane >> 4, l16 = lane & 15;

  // ones B-fragment (col 0 of a 16-col tile = 1): sums P rows via MFMA
  short8 onesf;
  {
    short ov = (l16 == 0) ? (short)0x3F80 : (short)0;
#pragma unroll
    for (int j = 0; j < 8; ++j) onesf[j] = ov;
  }

  // preload Q A-fragments (Q pre-scaled by log2e/8)
  short8 qf[2][2];
#pragma unroll
  for (int rt = 0; rt < 2; ++rt)
#pragma unroll
    for (int ks = 0; ks < 2; ++ks)
      qf[rt][ks] = *(const short8*)(Qp + (size_t)(n * 128 + w * 32 + rt * 16 + l16) * 64 + ks * 32 + quad * 8);

  floatx4 zf = {0.f, 0.f, 0.f, 0.f};
  floatx4 o[2][4];
  floatx4 osum[2];
#pragma unroll
  for (int i = 0; i < 2; ++i) {
    osum[i] = zf;
#pragma unroll
    for (int j = 0; j < 4; ++j) o[i][j] = zf;
  }

#pragma unroll
  for (int c = 0; c < 3; ++c) {
    int bk = n - 1 + c;
    bool inr = (c == 1) || (c == 0 ? (n > 0) : (n < 31));
    __syncthreads();   // prior chunk's kt/vt readers done before restage
    if (inr) {
      const short* kc_ = Kp + (size_t)bk * 128 * 64;
      int kr = tid >> 2, ksg = (tid & 3) * 16;
#pragma unroll
      for (int p = 0; p < 2; ++p) {
        int r2 = p * 64 + kr;
        *(short8*)(&kt[r2][ksg])     = *(const short8*)(kc_ + r2 * 64 + ksg);
        *(short8*)(&kt[r2][ksg + 8]) = *(const short8*)(kc_ + r2 * 64 + ksg + 8);
      }
      // V transpose-in-LDS: thread -> key (tid&31), d-seg (tid>>5)*8
      const short* vc_ = Vp + (size_t)bk * 128 * 64;
      int vkey = tid & 31, vsg = (tid >> 5) * 8;
#pragma unroll
      for (int p = 0; p < 4; ++p) {
        int r2 = p * 32 + vkey;
        short8 vv = *(const short8*)(vc_ + r2 * 64 + vsg);
#pragma unroll
        for (int j = 0; j < 8; ++j) vt[vsg + j][r2] = vv[j];
      }
    } else {
      short8 z8 = {0, 0, 0, 0, 0, 0, 0, 0};
      int kr = tid >> 2, ksg = (tid & 3) * 16;
#pragma unroll
      for (int p = 0; p < 2; ++p) {
        int r2 = p * 64 + kr;
        *(short8*)(&kt[r2][ksg])     = z8;
        *(short8*)(&kt[r2][ksg + 8]) = z8;
      }
      int vr = tid >> 2, vsg2 = (tid & 3) * 32;
#pragma unroll
      for (int q2 = 0; q2 < 4; ++q2) *(short8*)(&vt[vr][vsg2 + q2 * 8]) = z8;
    }
    __syncthreads();

    // S = Q K^T; skip fully-masked 16-col tiles (wave-uniform: wrt = w*2+rt)
    floatx4 s[2][8];
#pragma unroll
    for (int rt = 0; rt < 2; ++rt)
#pragma unroll
      for (int ct = 0; ct < 8; ++ct) s[rt][ct] = zf;
#pragma unroll
    for (int ct = 0; ct < 8; ++ct) {
      bool any = (c == 0) ? (ct >= w * 2) : (c == 2) ? (ct <= w * 2 + 1) : true;
      if (any) {
        short8 kf0 = *(const short8*)(&kt[ct * 16 + l16][quad * 8]);
        short8 kf1 = *(const short8*)(&kt[ct * 16 + l16][32 + quad * 8]);
#pragma unroll
        for (int rt = 0; rt < 2; ++rt) {
          bool valid = (c == 0) ? (ct >= w * 2 + rt) : (c == 2) ? (ct <= w * 2 + rt) : true;
          if (valid) {
            s[rt][ct] = MFMA_B16(qf[rt][0], kf0, s[rt][ct]);
            s[rt][ct] = MFMA_B16(qf[rt][1], kf1, s[rt][ct]);
          }
        }
      }
    }

    // P = exp2(S); per-element mask only on the diagonal tile; zero-fill
    // fully-masked tiles whose enclosing 32-key ks-tile is still live.
#pragma unroll
    for (int rt = 0; rt < 2; ++rt) {
      int wrt = w * 2 + rt;
#pragma unroll
      for (int ct = 0; ct < 8; ++ct) {
        bool tileMasked = (c == 0) ? (ct < wrt) : (c == 2) ? (ct > wrt) : false;
        bool ksDead = (c == 0) ? (2 * (ct >> 1) + 1 < wrt)
                    : (c == 2) ? (2 * (ct >> 1) > wrt) : false;
        bool diag = (c != 1) && (ct == wrt);
        if (ksDead) continue;
        if (tileMasked) {
#pragma unroll
          for (int rg = 0; rg < 4; ++rg)
            pl[w][rt * 16 + quad * 4 + rg][ct * 16 + l16] = 0;
        } else if (diag) {
#pragma unroll
          for (int rg = 0; rg < 4; ++rg) {
            int r16 = quad * 4 + rg;      // row within diag tile
            float p = exp2f(s[rt][ct][rg]);
            if (c == 0) p = (l16 < r16) ? 0.f : p;
            else        p = (l16 > r16) ? 0.f : p;
            pl[w][rt * 16 + r16][ct * 16 + l16] = f2bf_rtz(p);
          }
        } else {
#pragma unroll
          for (int rg = 0; rg < 4; ++rg)
            pl[w][rt * 16 + quad * 4 + rg][ct * 16 + l16] = f2bf_rtz(exp2f(s[rt][ct][rg]));
        }
      }
    }

    __syncthreads();   // order P-stores before cross-lane P-loads

    // O += P V ; row sums via ones-fragment; skip dead ks-tiles
#pragma unroll
    for (int ks = 0; ks < 4; ++ks) {
      bool anyrt = (c == 0) ? (2 * ks + 1 >= w * 2) : (c == 2) ? (2 * ks <= w * 2 + 1) : true;
      if (!anyrt) continue;
      short8 vf[4];
#pragma unroll
      for (int ct = 0; ct < 4; ++ct)
        vf[ct] = *(const short8*)(&vt[ct * 16 + l16][ks * 32 + quad * 8]);
#pragma unroll
      for (int rt = 0; rt < 2; ++rt) {
        int wrt = w * 2 + rt;
        bool ksDead = (c == 0) ? (2 * ks + 1 < wrt) : (c == 2) ? (2 * ks > wrt) : false;
        if (ksDead) continue;
        short8 pf = *(const short8*)(&pl[w][rt * 16 + l16][ks * 32 + quad * 8]);
#pragma unroll
        for (int ct = 0; ct < 4; ++ct) o[rt][ct] = MFMA_B16(pf, vf[ct], o[rt][ct]);
        osum[rt] = MFMA_B16(pf, onesf, osum[rt]);
      }
    }
  }

  // normalize + store to (B, L, C) bf16; sum lives in col 0 of the ones tile
#pragma unroll
  for (int rt = 0; rt < 2; ++rt) {
#pragma unroll
    for (int rg = 0; rg < 4; ++rg) {
      float ssum = __shfl(osum[rt][rg], lane & 48);
      float inv = 1.f / ssum;
      int r = n * 128 + w * 32 + rt * 16 + quad * 4 + rg;
#pragma unroll
      for (int ct = 0; ct < 4; ++ct)
        attnb[(size_t)(b * L + r) * 1024 + h * 64 + ct * 16 + l16] =
            f2bf(o[rt][ct][rg] * inv);
    }
  }
}

// ---------------- output projection GEMM: BM=128, BN=256 (fp32 out) ----------------
// (round-7 version, unchanged: 256 blocks = 1 round, vmcnt(2) boundary)
__global__ __launch_bounds__(512, 2) void gemm_out(
    const short* __restrict__ attnb, const short* __restrict__ wTo,
    const float* __restrict__ bo, float* __restrict__ outp) {
  __shared__ __align__(16) short As[2 * 8192];     // 2 x 128x64
  __shared__ __align__(16) short Bs[2 * 16384];    // 2 x 256x64

  int bid = blockIdx.x;            // 0..255
  int xcd = bid & 7;
  int idx = bid >> 3;              // 0..31
  int mb  = xcd * 8 + (idx & 7);   // 8-m stripe per XCD
  int nb  = idx >> 3;              // 0..3
  int m0 = mb * 128, n0 = nb * 256;

  const int tid = threadIdx.x;
  const int w = tid >> 6, lane = tid & 63, quad = lane >> 4, l16 = lane & 15;
  const int wm = w >> 2, wn = w & 3;
  const int srow = tid >> 3;
  const int scol = ((tid & 7) ^ (srow & 7)) * 8;

  floatx4 zf = {0.f, 0.f, 0.f, 0.f};
  floatx4 acc[4][4];
#pragma unroll
  for (int i = 0; i < 4; ++i)
#pragma unroll
    for (int j = 0; j < 4; ++j) acc[i][j] = zf;

  const short* gA = attnb + (size_t)(m0 + srow) * 1024 + scol;
  const short* gB = wTo + (size_t)(n0 + srow) * 1024 + scol;

  auto stA = [&](int buf, int q, int kt) {
    gload_lds16(gA + (size_t)q * 64 * 1024 + kt * 64,
                As + buf * 8192 + q * 4096 + w * 512);
  };
  auto stB = [&](int buf, int q, int kt) {
    gload_lds16(gB + (size_t)q * 64 * 1024 + kt * 64,
                Bs + buf * 16384 + q * 4096 + w * 512);
  };

  short8 aF[8], bF[4];
  auto ldA = [&](int buf) {
    const char* base = (const char*)(As + buf * 8192);
#pragma unroll
    for (int m = 0; m < 4; ++m)
#pragma unroll
      for (int kk = 0; kk < 2; ++kk) {
        int row = wm * 64 + m * 16 + l16;
        int off = row * 128 + kk * 64 + quad * 16;
        off ^= (row & 7) << 4;
        aF[m * 2 + kk] = *(const short8*)(base + off);
      }
  };
  auto ldB = [&](int buf, int nh) {
    const char* base = (const char*)(Bs + buf * 16384);
#pragma unroll
    for (int n = 0; n < 2; ++n)
#pragma unroll
      for (int kk = 0; kk < 2; ++kk) {
        int row = wn * 64 + nh * 32 + n * 16 + l16;
        int off = row * 128 + kk * 64 + quad * 16;
        off ^= (row & 7) << 4;
        bF[n * 2 + kk] = *(const short8*)(base + off);
      }
  };
  auto mm = [&](int nh) {
#pragma unroll
    for (int m = 0; m < 4; ++m)
#pragma unroll
      for (int n = 0; n < 2; ++n)
#pragma unroll
        for (int kk = 0; kk < 2; ++kk)
          acc[m][nh * 2 + n] =
              MFMA_B16(aF[m * 2 + kk], bF[n * 2 + kk], acc[m][nh * 2 + n]);
  };

  // prologue: tile0 (A0,A1,B0..B3) + tile1 (A0,A1); B(t1) comes at t=0 p0
  stA(0, 0, 0); stA(0, 1, 0);
  stB(0, 0, 0); stB(0, 1, 0); stB(0, 2, 0); stB(0, 3, 0);
  stA(1, 0, 1); stA(1, 1, 1);
  asm volatile("s_waitcnt vmcnt(2)" ::: "memory");
  __builtin_amdgcn_s_barrier();

#pragma unroll 2
  for (int t = 0; t < 16; ++t) {
    const int cb = t & 1, nbuf = cb ^ 1;
    // p0: ldA + ldB(nh0); stage B(t+1) -> other buf (fully retired last iter)
    ldA(cb);
    ldB(cb, 0);
    if (t + 1 < 16) {
      stB(nbuf, 0, t + 1); stB(nbuf, 1, t + 1);
      stB(nbuf, 2, t + 1); stB(nbuf, 3, t + 1);
    }
    __builtin_amdgcn_s_setprio(1); mm(0); __builtin_amdgcn_s_setprio(0);
    __builtin_amdgcn_s_barrier();
    // p1: ldB(nh1); stage A(t+2) -> this buf (A reads retired @p0)
    ldB(cb, 1);
    if (t + 2 < 16) { stA(cb, 0, t + 2); stA(cb, 1, t + 2); }
    __builtin_amdgcn_s_setprio(1); mm(1); __builtin_amdgcn_s_setprio(0);
    if (t + 2 < 16) {
      asm volatile("s_waitcnt vmcnt(2)" ::: "memory");  // t+1 fully landed
    } else {
      asm volatile("s_waitcnt vmcnt(0)" ::: "memory");  // tail drain
    }
    __builtin_amdgcn_s_barrier();
  }

#pragma unroll
  for (int mf = 0; mf < 4; ++mf)
#pragma unroll
    for (int nf = 0; nf < 4; ++nf)
#pragma unroll
      for (int rg = 0; rg < 4; ++rg) {
        int m = m0 + wm * 64 + mf * 16 + quad * 4 + rg;
        int cc = n0 + wn * 64 + nf * 16 + l16;
        outp[(size_t)m * 1024 + cc] = acc[mf][nf][rg] + bo[cc];
      }
}

extern "C" void kernel_launch(void* const* d_in, const int* in_sizes, int n_in,
                              void* d_out, int out_size, void* d_ws, size_t ws_size,
                              hipStream_t stream) {
  const float* x  = (const float*)d_in[0];
  const float* wq = (const float*)d_in[1];
  const float* bq = (const float*)d_in[2];
  const float* wk = (const float*)d_in[3];
  const float* bk = (const float*)d_in[4];
  const float* wv = (const float*)d_in[5];
  const float* bv = (const float*)d_in[6];
  const float* wo = (const float*)d_in[7];
  const float* bo = (const float*)d_in[8];

  char* ws = (char*)d_ws;
  short* xb    = (short*)ws;                   // [0,16M): x bf16
  short* wT    = (short*)(ws + (16u << 20));   // [16M,24M): 4x W^T bf16
  short* qkv   = (short*)(ws + (24u << 20));   // [24M,72M): Q,K,V in (B,H,L,D)
  short* attnb = (short*)(ws + (72u << 20));   // [72M,88M): attention out (B,L,C) bf16

  prep<<<12288, 256, 0, stream>>>((const float4*)x, (short4v*)xb, wq, wk, wv, wo, wT);
  gemm_qkv<<<384, 512, 0, stream>>>(xb, wT, bq, bk, bv, qkv);
  attn_kern<<<dim3(32, 16, 2), 256, 0, stream>>>(qkv, attnb);
  gemm_out<<<256, 512, 0, stream>>>(attnb, wT + 3u * 1024 * 1024, bo, (float*)d_out);
}

// Round 9
// 240.626 us; speedup vs baseline: 1.1844x; 1.1844x over previous
//
#include <hip/hip_runtime.h>

using short8  = __attribute__((ext_vector_type(8))) short;
using short4v = __attribute__((ext_vector_type(4))) short;
using floatx4 = __attribute__((ext_vector_type(4))) float;

#define MFMA_B16(a, b, c) __builtin_amdgcn_mfma_f32_16x16x32_bf16(a, b, c, 0, 0, 0)

__device__ __forceinline__ short f2bf(float f) {
  union { float f; unsigned u; } v; v.f = f;
  unsigned r = v.u + 0x7fffu + ((v.u >> 16) & 1u);
  return (short)(r >> 16);
}
// truncating cast (P>=0; bias cancels between PV numerator and ones-column denom)
__device__ __forceinline__ short f2bf_rtz(float f) {
  union { float f; unsigned u; } v; v.f = f;
  return (short)(v.u >> 16);
}

// async global->LDS, 16B per lane; lds dest = wave-uniform base + lane*16
__device__ __forceinline__ void gload_lds16(const short* g, short* l) {
  __builtin_amdgcn_global_load_lds(
      (const __attribute__((address_space(1))) unsigned int*)g,
      (__attribute__((address_space(3))) unsigned int*)l, 16, 0, 0);
}

// ---------------- prep: cast x -> bf16  +  transpose/cast weights ----------------
__global__ __launch_bounds__(256) void prep(
    const float4* __restrict__ x, short4v* __restrict__ xb,
    const float* __restrict__ w0, const float* __restrict__ w1,
    const float* __restrict__ w2, const float* __restrict__ w3,
    short* __restrict__ wT) {
  __shared__ float tile[32][33];
  int blk = blockIdx.x;
  if (blk < 8192) {
    int i = blk * 256 + threadIdx.x;
    float4 v = x[i];
    short4v o = { f2bf(v.x), f2bf(v.y), f2bf(v.z), f2bf(v.w) };
    xb[i] = o;
  } else {
    int r = blk - 8192;
    int z = r >> 10; r &= 1023;
    const float* w = z == 0 ? w0 : (z == 1 ? w1 : (z == 2 ? w2 : w3));
    short* out = wT + (size_t)z * 1024 * 1024;
    int n0 = (r & 31) * 32, k0 = (r >> 5) * 32;
    int tx = threadIdx.x & 31, ty = threadIdx.x >> 5;
#pragma unroll
    for (int i = 0; i < 4; ++i)
      tile[ty + i * 8][tx] = w[(size_t)(k0 + ty + i * 8) * 1024 + n0 + tx];
    __syncthreads();
#pragma unroll
    for (int i = 0; i < 4; ++i)
      out[(size_t)(n0 + ty + i * 8) * 1024 + k0 + tx] = f2bf(tile[tx][ty + i * 8]);
  }
}

// ---------------- QKV projection GEMM (round-0 structure, split per z) ----------------
// Reverted to the best-measured structure (round 0: 68.2 us for all 3 z).
// Split into 3 dispatches (z passed as an argument) so each dispatch is
// ~23 us: attn_kern / gemm_out / prep become visible in the top-5 profile.
// z=0: Q scaled by log2(e)/8; z=1: K; z=2: V.  All out (B,H,L,D) bf16.
__global__ __launch_bounds__(256) void gemm_qkv(
    const short* __restrict__ xb, const short* __restrict__ wT,
    const float* __restrict__ bq, const float* __restrict__ bk,
    const float* __restrict__ bv, short* __restrict__ qkv, int z) {
  const int K = 1024;
  const short* wt = wT + (size_t)z * 1024 * 1024;
  const float* bias = z == 0 ? bq : (z == 1 ? bk : bv);
  short* out = qkv + (size_t)z * 8192 * 1024;

  int m0 = blockIdx.x * 128, n0 = blockIdx.y * 128;
  __shared__ __align__(16) short a[128][32];   // unpadded: global_load_lds layout
  __shared__ __align__(16) short bt[128][32];
  int tid = threadIdx.x;
  int w = tid >> 6, lane = tid & 63, quad = lane >> 4, l16 = lane & 15;
  int wm = (w >> 1) * 64, wn = (w & 1) * 64;
  floatx4 zf = {0.f, 0.f, 0.f, 0.f};
  floatx4 acc[4][4];
#pragma unroll
  for (int i = 0; i < 4; ++i)
#pragma unroll
    for (int j = 0; j < 4; ++j) acc[i][j] = zf;

  int rowL = lane >> 2;          // 0..15
  int segL = (lane & 3) * 8;     // short offset within row
  const short* ga = xb + (size_t)(m0 + w * 32 + rowL) * K + segL;
  const short* gb = wt + (size_t)(n0 + w * 32 + rowL) * K + segL;
  short* la = &a[w * 32][0];
  short* lb = &bt[w * 32][0];

  for (int k0 = 0; k0 < K; k0 += 32) {
    __syncthreads();
    gload_lds16(ga + k0, la);
    gload_lds16(ga + (size_t)16 * K + k0, la + 16 * 32);
    gload_lds16(gb + k0, lb);
    gload_lds16(gb + (size_t)16 * K + k0, lb + 16 * 32);
    __syncthreads();
    short8 af[4], bf[4];
#pragma unroll
    for (int t = 0; t < 4; ++t) {
      af[t] = *(const short8*)(&a[wm + t * 16 + l16][quad * 8]);
      bf[t] = *(const short8*)(&bt[wn + t * 16 + l16][quad * 8]);
    }
#pragma unroll
    for (int i = 0; i < 4; ++i)
#pragma unroll
      for (int j = 0; j < 4; ++j)
        acc[i][j] = MFMA_B16(af[i], bf[j], acc[i][j]);
  }

  // Q pre-scaled by log2(e)/sqrt(D) so attention can use exp2
  float qs = (z == 0) ? 0.125f * 1.44269504f : 1.0f;
#pragma unroll
  for (int i = 0; i < 4; ++i)
#pragma unroll
    for (int j = 0; j < 4; ++j)
#pragma unroll
      for (int rg = 0; rg < 4; ++rg) {
        int m = m0 + wm + i * 16 + quad * 4 + rg;
        int cc = n0 + wn + j * 16 + l16;
        float v = (acc[i][j][rg] + bias[cc]) * qs;
        int b = m >> 12, l = m & 4095;
        int hh = cc >> 6, d = cc & 63;
        out[((size_t)(b * 16 + hh) * 4096 + l) * 64 + d] = f2bf(v);
      }
}

// ---------------- windowed attention (round-0 version, unchanged) ----------------
__global__ __launch_bounds__(256) void attn_kern(const short* __restrict__ qkv,
                                                 short* __restrict__ attnb) {
  const int L = 4096, H = 16;
  int n = blockIdx.x, h = blockIdx.y, b = blockIdx.z;
  const size_t hs = (size_t)L * 64;
  const short* Qp = qkv + (size_t)(b * H + h) * hs;
  const short* Kp = qkv + (size_t)8192 * 1024 + (size_t)(b * H + h) * hs;
  const short* Vp = qkv + (size_t)2 * 8192 * 1024 + (size_t)(b * H + h) * hs;

  __shared__ __align__(16) short kt[128][72];
  __shared__ __align__(16) short vt[64][136];   // vt[d][key]
  __shared__ __align__(16) short pl[4][32][136];

  int tid = threadIdx.x, w = tid >> 6, lane = tid & 63, quad = lane >> 4, l16 = lane & 15;

  // ones B-fragment (col 0 of a 16-col tile = 1): sums P rows via MFMA
  short8 onesf;
  {
    short ov = (l16 == 0) ? (short)0x3F80 : (short)0;
#pragma unroll
    for (int j = 0; j < 8; ++j) onesf[j] = ov;
  }

  // preload Q A-fragments (Q pre-scaled by log2e/8)
  short8 qf[2][2];
#pragma unroll
  for (int rt = 0; rt < 2; ++rt)
#pragma unroll
    for (int ks = 0; ks < 2; ++ks)
      qf[rt][ks] = *(const short8*)(Qp + (size_t)(n * 128 + w * 32 + rt * 16 + l16) * 64 + ks * 32 + quad * 8);

  floatx4 zf = {0.f, 0.f, 0.f, 0.f};
  floatx4 o[2][4];
  floatx4 osum[2];
#pragma unroll
  for (int i = 0; i < 2; ++i) {
    osum[i] = zf;
#pragma unroll
    for (int j = 0; j < 4; ++j) o[i][j] = zf;
  }

#pragma unroll
  for (int c = 0; c < 3; ++c) {
    int bk = n - 1 + c;
    bool inr = (c == 1) || (c == 0 ? (n > 0) : (n < 31));
    __syncthreads();   // prior chunk's kt/vt readers done before restage
    if (inr) {
      const short* kc_ = Kp + (size_t)bk * 128 * 64;
      int kr = tid >> 2, ksg = (tid & 3) * 16;
#pragma unroll
      for (int p = 0; p < 2; ++p) {
        int r2 = p * 64 + kr;
        *(short8*)(&kt[r2][ksg])     = *(const short8*)(kc_ + r2 * 64 + ksg);
        *(short8*)(&kt[r2][ksg + 8]) = *(const short8*)(kc_ + r2 * 64 + ksg + 8);
      }
      // V transpose-in-LDS: thread -> key (tid&31), d-seg (tid>>5)*8
      const short* vc_ = Vp + (size_t)bk * 128 * 64;
      int vkey = tid & 31, vsg = (tid >> 5) * 8;
#pragma unroll
      for (int p = 0; p < 4; ++p) {
        int r2 = p * 32 + vkey;
        short8 vv = *(const short8*)(vc_ + r2 * 64 + vsg);
#pragma unroll
        for (int j = 0; j < 8; ++j) vt[vsg + j][r2] = vv[j];
      }
    } else {
      short8 z8 = {0, 0, 0, 0, 0, 0, 0, 0};
      int kr = tid >> 2, ksg = (tid & 3) * 16;
#pragma unroll
      for (int p = 0; p < 2; ++p) {
        int r2 = p * 64 + kr;
        *(short8*)(&kt[r2][ksg])     = z8;
        *(short8*)(&kt[r2][ksg + 8]) = z8;
      }
      int vr = tid >> 2, vsg2 = (tid & 3) * 32;
#pragma unroll
      for (int q2 = 0; q2 < 4; ++q2) *(short8*)(&vt[vr][vsg2 + q2 * 8]) = z8;
    }
    __syncthreads();

    // S = Q K^T; skip fully-masked 16-col tiles (wave-uniform: wrt = w*2+rt)
    floatx4 s[2][8];
#pragma unroll
    for (int rt = 0; rt < 2; ++rt)
#pragma unroll
      for (int ct = 0; ct < 8; ++ct) s[rt][ct] = zf;
#pragma unroll
    for (int ct = 0; ct < 8; ++ct) {
      bool any = (c == 0) ? (ct >= w * 2) : (c == 2) ? (ct <= w * 2 + 1) : true;
      if (any) {
        short8 kf0 = *(const short8*)(&kt[ct * 16 + l16][quad * 8]);
        short8 kf1 = *(const short8*)(&kt[ct * 16 + l16][32 + quad * 8]);
#pragma unroll
        for (int rt = 0; rt < 2; ++rt) {
          bool valid = (c == 0) ? (ct >= w * 2 + rt) : (c == 2) ? (ct <= w * 2 + rt) : true;
          if (valid) {
            s[rt][ct] = MFMA_B16(qf[rt][0], kf0, s[rt][ct]);
            s[rt][ct] = MFMA_B16(qf[rt][1], kf1, s[rt][ct]);
          }
        }
      }
    }

    // P = exp2(S); per-element mask only on the diagonal tile; zero-fill
    // fully-masked tiles whose enclosing 32-key ks-tile is still live.
#pragma unroll
    for (int rt = 0; rt < 2; ++rt) {
      int wrt = w * 2 + rt;
#pragma unroll
      for (int ct = 0; ct < 8; ++ct) {
        bool tileMasked = (c == 0) ? (ct < wrt) : (c == 2) ? (ct > wrt) : false;
        bool ksDead = (c == 0) ? (2 * (ct >> 1) + 1 < wrt)
                    : (c == 2) ? (2 * (ct >> 1) > wrt) : false;
        bool diag = (c != 1) && (ct == wrt);
        if (ksDead) continue;
        if (tileMasked) {
#pragma unroll
          for (int rg = 0; rg < 4; ++rg)
            pl[w][rt * 16 + quad * 4 + rg][ct * 16 + l16] = 0;
        } else if (diag) {
#pragma unroll
          for (int rg = 0; rg < 4; ++rg) {
            int r16 = quad * 4 + rg;      // row within diag tile
            float p = exp2f(s[rt][ct][rg]);
            if (c == 0) p = (l16 < r16) ? 0.f : p;
            else        p = (l16 > r16) ? 0.f : p;
            pl[w][rt * 16 + r16][ct * 16 + l16] = f2bf_rtz(p);
          }
        } else {
#pragma unroll
          for (int rg = 0; rg < 4; ++rg)
            pl[w][rt * 16 + quad * 4 + rg][ct * 16 + l16] = f2bf_rtz(exp2f(s[rt][ct][rg]));
        }
      }
    }

    __syncthreads();   // order P-stores before cross-lane P-loads

    // O += P V ; row sums via ones-fragment; skip dead ks-tiles
#pragma unroll
    for (int ks = 0; ks < 4; ++ks) {
      bool anyrt = (c == 0) ? (2 * ks + 1 >= w * 2) : (c == 2) ? (2 * ks <= w * 2 + 1) : true;
      if (!anyrt) continue;
      short8 vf[4];
#pragma unroll
      for (int ct = 0; ct < 4; ++ct)
        vf[ct] = *(const short8*)(&vt[ct * 16 + l16][ks * 32 + quad * 8]);
#pragma unroll
      for (int rt = 0; rt < 2; ++rt) {
        int wrt = w * 2 + rt;
        bool ksDead = (c == 0) ? (2 * ks + 1 < wrt) : (c == 2) ? (2 * ks > wrt) : false;
        if (ksDead) continue;
        short8 pf = *(const short8*)(&pl[w][rt * 16 + l16][ks * 32 + quad * 8]);
#pragma unroll
        for (int ct = 0; ct < 4; ++ct) o[rt][ct] = MFMA_B16(pf, vf[ct], o[rt][ct]);
        osum[rt] = MFMA_B16(pf, onesf, osum[rt]);
      }
    }
  }

  // normalize + store to (B, L, C) bf16; sum lives in col 0 of the ones tile
#pragma unroll
  for (int rt = 0; rt < 2; ++rt) {
#pragma unroll
    for (int rg = 0; rg < 4; ++rg) {
      float ssum = __shfl(osum[rt][rg], lane & 48);
      float inv = 1.f / ssum;
      int r = n * 128 + w * 32 + rt * 16 + quad * 4 + rg;
#pragma unroll
      for (int ct = 0; ct < 4; ++ct)
        attnb[(size_t)(b * L + r) * 1024 + h * 64 + ct * 16 + l16] =
            f2bf(o[rt][ct][rg] * inv);
    }
  }
}

// ---------------- output projection GEMM (fp32 out), 128x128 (round-0) ----------------
__global__ __launch_bounds__(256) void gemm_out(
    const short* __restrict__ attnb, const short* __restrict__ wTo,
    const float* __restrict__ bo, float* __restrict__ outp) {
  const int K = 1024;
  int m0 = blockIdx.x * 128, n0 = blockIdx.y * 128;
  __shared__ __align__(16) short a[128][32];
  __shared__ __align__(16) short bt[128][32];
  int tid = threadIdx.x;
  int w = tid >> 6, lane = tid & 63, quad = lane >> 4, l16 = lane & 15;
  int wm = (w >> 1) * 64, wn = (w & 1) * 64;
  floatx4 zf = {0.f, 0.f, 0.f, 0.f};
  floatx4 acc[4][4];
#pragma unroll
  for (int i = 0; i < 4; ++i)
#pragma unroll
    for (int j = 0; j < 4; ++j) acc[i][j] = zf;

  int rowL = lane >> 2;
  int segL = (lane & 3) * 8;
  const short* ga = attnb + (size_t)(m0 + w * 32 + rowL) * K + segL;
  const short* gb = wTo + (size_t)(n0 + w * 32 + rowL) * K + segL;
  short* la = &a[w * 32][0];
  short* lb = &bt[w * 32][0];

  for (int k0 = 0; k0 < K; k0 += 32) {
    __syncthreads();
    gload_lds16(ga + k0, la);
    gload_lds16(ga + (size_t)16 * K + k0, la + 16 * 32);
    gload_lds16(gb + k0, lb);
    gload_lds16(gb + (size_t)16 * K + k0, lb + 16 * 32);
    __syncthreads();
    short8 af[4], bf[4];
#pragma unroll
    for (int t = 0; t < 4; ++t) {
      af[t] = *(const short8*)(&a[wm + t * 16 + l16][quad * 8]);
      bf[t] = *(const short8*)(&bt[wn + t * 16 + l16][quad * 8]);
    }
#pragma unroll
    for (int i = 0; i < 4; ++i)
#pragma unroll
      for (int j = 0; j < 4; ++j)
        acc[i][j] = MFMA_B16(af[i], bf[j], acc[i][j]);
  }
#pragma unroll
  for (int i = 0; i < 4; ++i)
#pragma unroll
    for (int j = 0; j < 4; ++j)
#pragma unroll
      for (int rg = 0; rg < 4; ++rg) {
        int m = m0 + wm + i * 16 + quad * 4 + rg;
        int c = n0 + wn + j * 16 + l16;
        outp[(size_t)m * 1024 + c] = acc[i][j][rg] + bo[c];
      }
}

extern "C" void kernel_launch(void* const* d_in, const int* in_sizes, int n_in,
                              void* d_out, int out_size, void* d_ws, size_t ws_size,
                              hipStream_t stream) {
  const float* x  = (const float*)d_in[0];
  const float* wq = (const float*)d_in[1];
  const float* bq = (const float*)d_in[2];
  const float* wk = (const float*)d_in[3];
  const float* bk = (const float*)d_in[4];
  const float* wv = (const float*)d_in[5];
  const float* bv = (const float*)d_in[6];
  const float* wo = (const float*)d_in[7];
  const float* bo = (const float*)d_in[8];

  char* ws = (char*)d_ws;
  short* xb    = (short*)ws;                   // [0,16M): x bf16
  short* wT    = (short*)(ws + (16u << 20));   // [16M,24M): 4x W^T bf16
  short* qkv   = (short*)(ws + (24u << 20));   // [24M,72M): Q,K,V in (B,H,L,D)
  short* attnb = (short*)(ws + (72u << 20));   // [72M,88M): attention out (B,L,C) bf16

  prep<<<12288, 256, 0, stream>>>((const float4*)x, (short4v*)xb, wq, wk, wv, wo, wT);
  // split per z for profiler visibility (each ~23 us < attn/gemm_out)
  gemm_qkv<<<dim3(64, 8), 256, 0, stream>>>(xb, wT, bq, bk, bv, qkv, 0);
  gemm_qkv<<<dim3(64, 8), 256, 0, stream>>>(xb, wT, bq, bk, bv, qkv, 1);
  gemm_qkv<<<dim3(64, 8), 256, 0, stream>>>(xb, wT, bq, bk, bv, qkv, 2);
  attn_kern<<<dim3(32, 16, 2), 256, 0, stream>>>(qkv, attnb);
  gemm_out<<<dim3(64, 8), 256, 0, stream>>>(attnb, wT + 3u * 1024 * 1024, bo, (float*)d_out);
}

// Round 10
// 223.187 us; speedup vs baseline: 1.2769x; 1.0781x over previous
//
#include <hip/hip_runtime.h>

using short8  = __attribute__((ext_vector_type(8))) short;
using short4v = __attribute__((ext_vector_type(4))) short;
using floatx4 = __attribute__((ext_vector_type(4))) float;

#define MFMA_B16(a, b, c) __builtin_amdgcn_mfma_f32_16x16x32_bf16(a, b, c, 0, 0, 0)

__device__ __forceinline__ short f2bf(float f) {
  union { float f; unsigned u; } v; v.f = f;
  unsigned r = v.u + 0x7fffu + ((v.u >> 16) & 1u);
  return (short)(r >> 16);
}
// truncating cast (P>=0; bias cancels between PV numerator and ones-column denom)
__device__ __forceinline__ short f2bf_rtz(float f) {
  union { float f; unsigned u; } v; v.f = f;
  return (short)(v.u >> 16);
}

// async global->LDS, 16B per lane; lds dest = wave-uniform base + lane*16
__device__ __forceinline__ void gload_lds16(const short* g, short* l) {
  __builtin_amdgcn_global_load_lds(
      (const __attribute__((address_space(1))) unsigned int*)g,
      (__attribute__((address_space(3))) unsigned int*)l, 16, 0, 0);
}

// ---------------- prep: cast x -> bf16  +  transpose/cast weights ----------------
__global__ __launch_bounds__(256) void prep(
    const float4* __restrict__ x, short4v* __restrict__ xb,
    const float* __restrict__ w0, const float* __restrict__ w1,
    const float* __restrict__ w2, const float* __restrict__ w3,
    short* __restrict__ wT) {
  __shared__ float tile[32][33];
  int blk = blockIdx.x;
  if (blk < 8192) {
    int i = blk * 256 + threadIdx.x;
    float4 v = x[i];
    short4v o = { f2bf(v.x), f2bf(v.y), f2bf(v.z), f2bf(v.w) };
    xb[i] = o;
  } else {
    int r = blk - 8192;
    int z = r >> 10; r &= 1023;
    const float* w = z == 0 ? w0 : (z == 1 ? w1 : (z == 2 ? w2 : w3));
    short* out = wT + (size_t)z * 1024 * 1024;
    int n0 = (r & 31) * 32, k0 = (r >> 5) * 32;
    int tx = threadIdx.x & 31, ty = threadIdx.x >> 5;
#pragma unroll
    for (int i = 0; i < 4; ++i)
      tile[ty + i * 8][tx] = w[(size_t)(k0 + ty + i * 8) * 1024 + n0 + tx];
    __syncthreads();
#pragma unroll
    for (int i = 0; i < 4; ++i)
      out[(size_t)(n0 + ty + i * 8) * 1024 + k0 + tx] = f2bf(tile[tx][ty + i * 8]);
  }
}

// ---------------- QKV projection GEMM (round-0 fused, BK=32, 128x128) ----------------
// z=0: Q scaled by log2(e)/8; z=1: K; z=2: V.  All out (B,H,L,D) bf16.
__global__ __launch_bounds__(256) void gemm_qkv(
    const short* __restrict__ xb, const short* __restrict__ wT,
    const float* __restrict__ bq, const float* __restrict__ bk,
    const float* __restrict__ bv, short* __restrict__ qkv) {
  const int K = 1024;
  int z = blockIdx.z;
  const short* wt = wT + (size_t)z * 1024 * 1024;
  const float* bias = z == 0 ? bq : (z == 1 ? bk : bv);
  short* out = qkv + (size_t)z * 8192 * 1024;

  int m0 = blockIdx.x * 128, n0 = blockIdx.y * 128;
  __shared__ __align__(16) short a[128][32];   // unpadded: global_load_lds layout
  __shared__ __align__(16) short bt[128][32];
  int tid = threadIdx.x;
  int w = tid >> 6, lane = tid & 63, quad = lane >> 4, l16 = lane & 15;
  int wm = (w >> 1) * 64, wn = (w & 1) * 64;
  floatx4 zf = {0.f, 0.f, 0.f, 0.f};
  floatx4 acc[4][4];
#pragma unroll
  for (int i = 0; i < 4; ++i)
#pragma unroll
    for (int j = 0; j < 4; ++j) acc[i][j] = zf;

  int rowL = lane >> 2;          // 0..15
  int segL = (lane & 3) * 8;     // short offset within row
  const short* ga = xb + (size_t)(m0 + w * 32 + rowL) * K + segL;
  const short* gb = wt + (size_t)(n0 + w * 32 + rowL) * K + segL;
  short* la = &a[w * 32][0];
  short* lb = &bt[w * 32][0];

  for (int k0 = 0; k0 < K; k0 += 32) {
    __syncthreads();
    gload_lds16(ga + k0, la);
    gload_lds16(ga + (size_t)16 * K + k0, la + 16 * 32);
    gload_lds16(gb + k0, lb);
    gload_lds16(gb + (size_t)16 * K + k0, lb + 16 * 32);
    __syncthreads();
    short8 af[4], bf[4];
#pragma unroll
    for (int t = 0; t < 4; ++t) {
      af[t] = *(const short8*)(&a[wm + t * 16 + l16][quad * 8]);
      bf[t] = *(const short8*)(&bt[wn + t * 16 + l16][quad * 8]);
    }
#pragma unroll
    for (int i = 0; i < 4; ++i)
#pragma unroll
      for (int j = 0; j < 4; ++j)
        acc[i][j] = MFMA_B16(af[i], bf[j], acc[i][j]);
  }

  // Q pre-scaled by log2(e)/sqrt(D) so attention can use exp2
  float qs = (z == 0) ? 0.125f * 1.44269504f : 1.0f;
#pragma unroll
  for (int i = 0; i < 4; ++i)
#pragma unroll
    for (int j = 0; j < 4; ++j)
#pragma unroll
      for (int rg = 0; rg < 4; ++rg) {
        int m = m0 + wm + i * 16 + quad * 4 + rg;
        int cc = n0 + wn + j * 16 + l16;
        float v = (acc[i][j][rg] + bias[cc]) * qs;
        int b = m >> 12, l = m & 4095;
        int hh = cc >> 6, d = cc & 63;
        out[((size_t)(b * 16 + hh) * 4096 + l) * 64 + d] = f2bf(v);
      }
}

// ---------------- windowed attention: split-pl (3 blocks/CU) ----------------
// ROUND-10 CHANGE: pl halved to [4][32][72] (PV runs in two 64-key passes) ->
// LDS 70656 -> 54272 B -> 3 blocks/CU (was 2). pl is WAVE-PRIVATE (always
// pl[w]), so the P-store->P-load ordering needs only a wave-local
// lgkmcnt(0) fence (same-wave LDS ops are in-order; cross-lane visibility
// after the counted wait) -- the block barrier there is removed.
__global__ __launch_bounds__(256) void attn_kern(const short* __restrict__ qkv,
                                                 short* __restrict__ attnb) {
  const int L = 4096, H = 16;
  int n = blockIdx.x, h = blockIdx.y, b = blockIdx.z;
  const size_t hs = (size_t)L * 64;
  const short* Qp = qkv + (size_t)(b * H + h) * hs;
  const short* Kp = qkv + (size_t)8192 * 1024 + (size_t)(b * H + h) * hs;
  const short* Vp = qkv + (size_t)2 * 8192 * 1024 + (size_t)(b * H + h) * hs;

  __shared__ __align__(16) short kt[128][72];
  __shared__ __align__(16) short vt[64][136];   // vt[d][key]
  __shared__ __align__(16) short pl[4][32][72]; // per-wave P half-buffer

  int tid = threadIdx.x, w = tid >> 6, lane = tid & 63, quad = lane >> 4, l16 = lane & 15;

  // ones B-fragment (col 0 of a 16-col tile = 1): sums P rows via MFMA
  short8 onesf;
  {
    short ov = (l16 == 0) ? (short)0x3F80 : (short)0;
#pragma unroll
    for (int j = 0; j < 8; ++j) onesf[j] = ov;
  }

  // preload Q A-fragments (Q pre-scaled by log2e/8)
  short8 qf[2][2];
#pragma unroll
  for (int rt = 0; rt < 2; ++rt)
#pragma unroll
    for (int ks = 0; ks < 2; ++ks)
      qf[rt][ks] = *(const short8*)(Qp + (size_t)(n * 128 + w * 32 + rt * 16 + l16) * 64 + ks * 32 + quad * 8);

  floatx4 zf = {0.f, 0.f, 0.f, 0.f};
  floatx4 o[2][4];
  floatx4 osum[2];
#pragma unroll
  for (int i = 0; i < 2; ++i) {
    osum[i] = zf;
#pragma unroll
    for (int j = 0; j < 4; ++j) o[i][j] = zf;
  }

#pragma unroll
  for (int c = 0; c < 3; ++c) {
    int bk = n - 1 + c;
    bool inr = (c == 1) || (c == 0 ? (n > 0) : (n < 31));
    __syncthreads();   // prior chunk's kt/vt readers done before restage
    if (inr) {
      const short* kc_ = Kp + (size_t)bk * 128 * 64;
      int kr = tid >> 2, ksg = (tid & 3) * 16;
#pragma unroll
      for (int p = 0; p < 2; ++p) {
        int r2 = p * 64 + kr;
        *(short8*)(&kt[r2][ksg])     = *(const short8*)(kc_ + r2 * 64 + ksg);
        *(short8*)(&kt[r2][ksg + 8]) = *(const short8*)(kc_ + r2 * 64 + ksg + 8);
      }
      // V transpose-in-LDS: thread -> key (tid&31), d-seg (tid>>5)*8
      const short* vc_ = Vp + (size_t)bk * 128 * 64;
      int vkey = tid & 31, vsg = (tid >> 5) * 8;
#pragma unroll
      for (int p = 0; p < 4; ++p) {
        int r2 = p * 32 + vkey;
        short8 vv = *(const short8*)(vc_ + r2 * 64 + vsg);
#pragma unroll
        for (int j = 0; j < 8; ++j) vt[vsg + j][r2] = vv[j];
      }
    } else {
      short8 z8 = {0, 0, 0, 0, 0, 0, 0, 0};
      int kr = tid >> 2, ksg = (tid & 3) * 16;
#pragma unroll
      for (int p = 0; p < 2; ++p) {
        int r2 = p * 64 + kr;
        *(short8*)(&kt[r2][ksg])     = z8;
        *(short8*)(&kt[r2][ksg + 8]) = z8;
      }
      int vr = tid >> 2, vsg2 = (tid & 3) * 32;
#pragma unroll
      for (int q2 = 0; q2 < 4; ++q2) *(short8*)(&vt[vr][vsg2 + q2 * 8]) = z8;
    }
    __syncthreads();

    // S = Q K^T; skip fully-masked 16-col tiles (wave-uniform: wrt = w*2+rt)
    floatx4 s[2][8];
#pragma unroll
    for (int rt = 0; rt < 2; ++rt)
#pragma unroll
      for (int ct = 0; ct < 8; ++ct) s[rt][ct] = zf;
#pragma unroll
    for (int ct = 0; ct < 8; ++ct) {
      bool any = (c == 0) ? (ct >= w * 2) : (c == 2) ? (ct <= w * 2 + 1) : true;
      if (any) {
        short8 kf0 = *(const short8*)(&kt[ct * 16 + l16][quad * 8]);
        short8 kf1 = *(const short8*)(&kt[ct * 16 + l16][32 + quad * 8]);
#pragma unroll
        for (int rt = 0; rt < 2; ++rt) {
          bool valid = (c == 0) ? (ct >= w * 2 + rt) : (c == 2) ? (ct <= w * 2 + rt) : true;
          if (valid) {
            s[rt][ct] = MFMA_B16(qf[rt][0], kf0, s[rt][ct]);
            s[rt][ct] = MFMA_B16(qf[rt][1], kf1, s[rt][ct]);
          }
        }
      }
    }

    // Two halves: hf=0 -> key cols 0..63 (ct 0..3, ks 0..1);
    //             hf=1 -> key cols 64..127 (ct 4..7, ks 2..3).
#pragma unroll
    for (int hf = 0; hf < 2; ++hf) {
      // P = exp2(S) for this half; per-element mask only on the diagonal tile
#pragma unroll
      for (int rt = 0; rt < 2; ++rt) {
        int wrt = w * 2 + rt;
#pragma unroll
        for (int c4 = 0; c4 < 4; ++c4) {
          int ct = hf * 4 + c4;
          bool tileMasked = (c == 0) ? (ct < wrt) : (c == 2) ? (ct > wrt) : false;
          bool ksDead = (c == 0) ? (2 * (ct >> 1) + 1 < wrt)
                      : (c == 2) ? (2 * (ct >> 1) > wrt) : false;
          bool diag = (c != 1) && (ct == wrt);
          if (ksDead) continue;
          if (tileMasked) {
#pragma unroll
            for (int rg = 0; rg < 4; ++rg)
              pl[w][rt * 16 + quad * 4 + rg][c4 * 16 + l16] = 0;
          } else if (diag) {
#pragma unroll
            for (int rg = 0; rg < 4; ++rg) {
              int r16 = quad * 4 + rg;      // row within diag tile
              float p = exp2f(s[rt][ct][rg]);
              if (c == 0) p = (l16 < r16) ? 0.f : p;
              else        p = (l16 > r16) ? 0.f : p;
              pl[w][rt * 16 + r16][c4 * 16 + l16] = f2bf_rtz(p);
            }
          } else {
#pragma unroll
            for (int rg = 0; rg < 4; ++rg)
              pl[w][rt * 16 + quad * 4 + rg][c4 * 16 + l16] = f2bf_rtz(exp2f(s[rt][ct][rg]));
          }
        }
      }

      // wave-local fence: pl is per-wave; same-wave LDS ops are in-order,
      // counted wait makes cross-lane writes visible to the pf reads below.
      asm volatile("s_waitcnt lgkmcnt(0)" ::: "memory");
      __builtin_amdgcn_sched_barrier(0);

      // O += P V for this half's two 32-key stripes; skip dead ks-tiles
#pragma unroll
      for (int k2 = 0; k2 < 2; ++k2) {
        int ks = hf * 2 + k2;
        bool anyrt = (c == 0) ? (2 * ks + 1 >= w * 2) : (c == 2) ? (2 * ks <= w * 2 + 1) : true;
        if (!anyrt) continue;
        short8 vf[4];
#pragma unroll
        for (int ct = 0; ct < 4; ++ct)
          vf[ct] = *(const short8*)(&vt[ct * 16 + l16][ks * 32 + quad * 8]);
#pragma unroll
        for (int rt = 0; rt < 2; ++rt) {
          int wrt = w * 2 + rt;
          bool ksDead = (c == 0) ? (2 * ks + 1 < wrt) : (c == 2) ? (2 * ks > wrt) : false;
          if (ksDead) continue;
          short8 pf = *(const short8*)(&pl[w][rt * 16 + l16][k2 * 32 + quad * 8]);
#pragma unroll
          for (int ct = 0; ct < 4; ++ct) o[rt][ct] = MFMA_B16(pf, vf[ct], o[rt][ct]);
          osum[rt] = MFMA_B16(pf, onesf, osum[rt]);
        }
      }
    }
  }

  // normalize + store to (B, L, C) bf16; sum lives in col 0 of the ones tile
#pragma unroll
  for (int rt = 0; rt < 2; ++rt) {
#pragma unroll
    for (int rg = 0; rg < 4; ++rg) {
      float ssum = __shfl(osum[rt][rg], lane & 48);
      float inv = 1.f / ssum;
      int r = n * 128 + w * 32 + rt * 16 + quad * 4 + rg;
#pragma unroll
      for (int ct = 0; ct < 4; ++ct)
        attnb[(size_t)(b * L + r) * 1024 + h * 64 + ct * 16 + l16] =
            f2bf(o[rt][ct][rg] * inv);
    }
  }
}

// ---------------- output projection GEMM (fp32 out), 128x128 (round-0) ----------------
__global__ __launch_bounds__(256) void gemm_out(
    const short* __restrict__ attnb, const short* __restrict__ wTo,
    const float* __restrict__ bo, float* __restrict__ outp) {
  const int K = 1024;
  int m0 = blockIdx.x * 128, n0 = blockIdx.y * 128;
  __shared__ __align__(16) short a[128][32];
  __shared__ __align__(16) short bt[128][32];
  int tid = threadIdx.x;
  int w = tid >> 6, lane = tid & 63, quad = lane >> 4, l16 = lane & 15;
  int wm = (w >> 1) * 64, wn = (w & 1) * 64;
  floatx4 zf = {0.f, 0.f, 0.f, 0.f};
  floatx4 acc[4][4];
#pragma unroll
  for (int i = 0; i < 4; ++i)
#pragma unroll
    for (int j = 0; j < 4; ++j) acc[i][j] = zf;

  int rowL = lane >> 2;
  int segL = (lane & 3) * 8;
  const short* ga = attnb + (size_t)(m0 + w * 32 + rowL) * K + segL;
  const short* gb = wTo + (size_t)(n0 + w * 32 + rowL) * K + segL;
  short* la = &a[w * 32][0];
  short* lb = &bt[w * 32][0];

  for (int k0 = 0; k0 < K; k0 += 32) {
    __syncthreads();
    gload_lds16(ga + k0, la);
    gload_lds16(ga + (size_t)16 * K + k0, la + 16 * 32);
    gload_lds16(gb + k0, lb);
    gload_lds16(gb + (size_t)16 * K + k0, lb + 16 * 32);
    __syncthreads();
    short8 af[4], bf[4];
#pragma unroll
    for (int t = 0; t < 4; ++t) {
      af[t] = *(const short8*)(&a[wm + t * 16 + l16][quad * 8]);
      bf[t] = *(const short8*)(&bt[wn + t * 16 + l16][quad * 8]);
    }
#pragma unroll
    for (int i = 0; i < 4; ++i)
#pragma unroll
      for (int j = 0; j < 4; ++j)
        acc[i][j] = MFMA_B16(af[i], bf[j], acc[i][j]);
  }
#pragma unroll
  for (int i = 0; i < 4; ++i)
#pragma unroll
    for (int j = 0; j < 4; ++j)
#pragma unroll
      for (int rg = 0; rg < 4; ++rg) {
        int m = m0 + wm + i * 16 + quad * 4 + rg;
        int c = n0 + wn + j * 16 + l16;
        outp[(size_t)m * 1024 + c] = acc[i][j][rg] + bo[c];
      }
}

extern "C" void kernel_launch(void* const* d_in, const int* in_sizes, int n_in,
                              void* d_out, int out_size, void* d_ws, size_t ws_size,
                              hipStream_t stream) {
  const float* x  = (const float*)d_in[0];
  const float* wq = (const float*)d_in[1];
  const float* bq = (const float*)d_in[2];
  const float* wk = (const float*)d_in[3];
  const float* bk = (const float*)d_in[4];
  const float* wv = (const float*)d_in[5];
  const float* bv = (const float*)d_in[6];
  const float* wo = (const float*)d_in[7];
  const float* bo = (const float*)d_in[8];

  char* ws = (char*)d_ws;
  short* xb    = (short*)ws;                   // [0,16M): x bf16
  short* wT    = (short*)(ws + (16u << 20));   // [16M,24M): 4x W^T bf16
  short* qkv   = (short*)(ws + (24u << 20));   // [24M,72M): Q,K,V in (B,H,L,D)
  short* attnb = (short*)(ws + (72u << 20));   // [72M,88M): attention out (B,L,C) bf16

  prep<<<12288, 256, 0, stream>>>((const float4*)x, (short4v*)xb, wq, wk, wv, wo, wT);
  gemm_qkv<<<dim3(64, 8, 3), 256, 0, stream>>>(xb, wT, bq, bk, bv, qkv);
  attn_kern<<<dim3(32, 16, 2), 256, 0, stream>>>(qkv, attnb);
  gemm_out<<<dim3(64, 8), 256, 0, stream>>>(attnb, wT + 3u * 1024 * 1024, bo, (float*)d_out);
}